// Round 1
// baseline (1213.492 us; speedup 1.0000x reference)
//
#include <hip/hip_runtime.h>
#include <math.h>

#define NCOMP 32768
#define LDIM  128
#define HDIM  512
#define DDIM  256
#define BROWS 512
#define KTOP  16

// -0.5 * D * log(2*pi)
#define NEG_HALF_D_LOG2PI (-235.24844f)

// ------------------------------------------------------------------
// Build X' from x:  X'[b, d] = x^2   (pairs with a_n = -0.5/var)
//                   X'[b, 256+d] = x (pairs with m_n = mu/var)
// ------------------------------------------------------------------
__global__ __launch_bounds__(256) void xprime_kernel(const float* __restrict__ x,
                                                     float* __restrict__ xp) {
  int i = blockIdx.x * 256 + threadIdx.x;     // over 512*256
  int b = i >> 8, d = i & 255;
  float xv = x[i];
  xp[(size_t)b * 512 + d]       = xv * xv;
  xp[(size_t)b * 512 + 256 + d] = xv;
}

// ------------------------------------------------------------------
// Tiled fp32 GEMM: C[M,Nn] = epi(A[M,K] @ op(B) + bias)
// BT=false: B is [K,Nn] row-major.  BT=true: B is [Nn,K] row-major (A@B^T).
// EPI: 1 = +bias[n],  2 = relu(+bias[n])
// All dims multiples of 64/32 in this problem -> no bounds checks.
// ------------------------------------------------------------------
template<int EPI, bool BT>
__global__ __launch_bounds__(256) void gemm64(const float* __restrict__ A,
                                              const float* __restrict__ B,
                                              const float* __restrict__ bias,
                                              float* __restrict__ C,
                                              int M, int Nn, int K) {
  const int BM = 64, BN = 64, BK = 32;
  __shared__ float As[BM][BK + 1];
  __shared__ float Bs[BK][BN + 1];
  const int lin = threadIdx.x;
  const int m0 = blockIdx.y * BM;
  const int n0 = blockIdx.x * BN;
  const int ty = lin >> 4, tx = lin & 15;
  float acc[4][4] = {};

  for (int k0 = 0; k0 < K; k0 += BK) {
    #pragma unroll
    for (int i = lin; i < BM * BK; i += 256) {
      int r = i >> 5, cc = i & 31;
      As[r][cc] = A[(size_t)(m0 + r) * K + k0 + cc];
    }
    if (!BT) {
      #pragma unroll
      for (int i = lin; i < BK * BN; i += 256) {
        int r = i >> 6, cc = i & 63;
        Bs[r][cc] = B[(size_t)(k0 + r) * Nn + n0 + cc];
      }
    } else {
      #pragma unroll
      for (int i = lin; i < BK * BN; i += 256) {
        int nn = i >> 5, kk = i & 31;
        Bs[kk][nn] = B[(size_t)(n0 + nn) * K + k0 + kk];
      }
    }
    __syncthreads();
    #pragma unroll
    for (int kk = 0; kk < BK; ++kk) {
      float a[4], bb[4];
      #pragma unroll
      for (int i = 0; i < 4; i++) a[i] = As[ty * 4 + i][kk];
      #pragma unroll
      for (int j = 0; j < 4; j++) bb[j] = Bs[kk][tx * 4 + j];
      #pragma unroll
      for (int i = 0; i < 4; i++)
        #pragma unroll
        for (int j = 0; j < 4; j++)
          acc[i][j] = fmaf(a[i], bb[j], acc[i][j]);
    }
    __syncthreads();
  }

  #pragma unroll
  for (int i = 0; i < 4; i++) {
    int m = m0 + ty * 4 + i;
    #pragma unroll
    for (int j = 0; j < 4; j++) {
      int n = n0 + tx * 4 + j;
      float val = acc[i][j];
      if (EPI >= 1) val += bias[n];
      if (EPI == 2) val = fmaxf(val, 0.f);
      C[(size_t)m * Nn + n] = val;
    }
  }
}

// ------------------------------------------------------------------
// raw[n, 0:256] = mu, raw[n, 256:512] = logvar  --->  in place:
//   P[n, d]      = -0.5 / var
//   P[n, 256+d]  = mu / var
//   c[n]         = -0.5*sum(mu^2/var) - sum(log std) - 0.5*D*log(2pi)
// ------------------------------------------------------------------
__global__ __launch_bounds__(256) void params_kernel(float* __restrict__ raw,
                                                     float* __restrict__ cvec) {
  const int n = blockIdx.x;
  const int tid = threadIdx.x;                 // 256 threads, one per d
  size_t base = (size_t)n * 512;
  float mu = raw[base + tid];
  float lv = raw[base + 256 + tid];
  float sp = (lv > 20.f) ? lv : log1pf(expf(lv));
  float sd = fminf(fmaxf(sp + 0.1f, 0.1f), 1.0f);
  float iv = 1.0f / (sd * sd);
  raw[base + tid]       = -0.5f * iv;
  raw[base + 256 + tid] = mu * iv;
  float part = -0.5f * mu * mu * iv - logf(sd);

  // block reduce (4 waves of 64)
  #pragma unroll
  for (int off = 32; off > 0; off >>= 1) part += __shfl_down(part, off, 64);
  __shared__ float red[4];
  if ((tid & 63) == 0) red[tid >> 6] = part;
  __syncthreads();
  if (tid == 0)
    cvec[n] = (red[0] + red[1] + red[2] + red[3]) + NEG_HALF_D_LOG2PI;
}

// ------------------------------------------------------------------
// Top-16 per row of scores = lp[b,:] + log_w[:], output lp at chosen idx.
// Tie-break: lower index wins (matches jax.lax.top_k).
// ------------------------------------------------------------------
__device__ __forceinline__ bool beats(float s, int n, float v, int i) {
  return (s > v) || (s == v && n < i);
}

__device__ __forceinline__ void insert16(float (&v)[16], int (&id)[16],
                                         float s, int n) {
  if (!beats(s, n, v[15], id[15])) return;
  #pragma unroll
  for (int i = 15; i >= 1; --i) {
    bool up   = beats(s, n, v[i - 1], id[i - 1]);
    bool here = beats(s, n, v[i], id[i]);
    float nv = up ? v[i - 1] : (here ? s : v[i]);
    int   ni = up ? id[i - 1] : (here ? n : id[i]);
    v[i] = nv; id[i] = ni;
  }
  if (beats(s, n, v[0], id[0])) { v[0] = s; id[0] = n; }
}

__global__ __launch_bounds__(256) void topk_kernel(const float* __restrict__ lp,
                                                   const float* __restrict__ log_w,
                                                   float* __restrict__ out) {
  const int b = blockIdx.x;
  const int tid = threadIdx.x;
  const float* row = lp + (size_t)b * NCOMP;

  float v[16]; int id[16];
  #pragma unroll
  for (int i = 0; i < 16; i++) { v[i] = -INFINITY; id[i] = 0x7fffffff; }

  for (int n = tid; n < NCOMP; n += 256) {
    float s = row[n] + log_w[n];
    insert16(v, id, s, n);
  }

  __shared__ float sv[256 * 16];
  __shared__ int   sid[256 * 16];
  #pragma unroll
  for (int i = 0; i < 16; i++) { sv[tid * 16 + i] = v[i]; sid[tid * 16 + i] = id[i]; }
  __syncthreads();

  // stage A: 16 threads each merge 16 lists
  if (tid < 16) {
    #pragma unroll
    for (int i = 0; i < 16; i++) { v[i] = -INFINITY; id[i] = 0x7fffffff; }
    for (int t = tid; t < 256; t += 16)
      for (int i = 0; i < 16; i++)
        insert16(v, id, sv[t * 16 + i], sid[t * 16 + i]);
  }
  __syncthreads();
  if (tid < 16) {
    #pragma unroll
    for (int i = 0; i < 16; i++) { sv[tid * 16 + i] = v[i]; sid[tid * 16 + i] = id[i]; }
  }
  __syncthreads();

  // stage B: thread 0 merges the 16 survivors' lists
  if (tid == 0) {
    #pragma unroll
    for (int i = 0; i < 16; i++) { v[i] = -INFINITY; id[i] = 0x7fffffff; }
    for (int t = 0; t < 16; t++)
      for (int i = 0; i < 16; i++)
        insert16(v, id, sv[t * 16 + i], sid[t * 16 + i]);
    #pragma unroll
    for (int i = 0; i < 16; i++)
      out[(size_t)b * KTOP + i] = row[id[i]];   // lp (not score) at top-k index
  }
}

// ------------------------------------------------------------------
extern "C" void kernel_launch(void* const* d_in, const int* in_sizes, int n_in,
                              void* d_out, int out_size, void* d_ws, size_t ws_size,
                              hipStream_t stream) {
  const float* x     = (const float*)d_in[0];
  const float* log_w = (const float*)d_in[1];
  const float* z     = (const float*)d_in[2];
  const float* W1    = (const float*)d_in[3];
  const float* b1    = (const float*)d_in[4];
  const float* W2    = (const float*)d_in[5];
  const float* b2    = (const float*)d_in[6];
  float* out = (float*)d_out;

  float* h    = (float*)d_ws;                      // [N, H]   64MB (reused as lp)
  float* raw  = h + (size_t)NCOMP * HDIM;          // [N, 512] 64MB (-> P in place)
  float* cvec = raw + (size_t)NCOMP * HDIM;        // [N]
  float* xp   = cvec + NCOMP;                      // [B, 512] 1MB
  float* lp   = h;                                 // [B, N]   reuses h

  // 1. X' from x
  hipLaunchKernelGGL(xprime_kernel, dim3((BROWS * DDIM) / 256), dim3(256), 0, stream,
                     x, xp);
  // 2. h = relu(z @ W1 + b1)      [32768,128]x[128,512]
  hipLaunchKernelGGL((gemm64<2, false>), dim3(HDIM / 64, NCOMP / 64), dim3(256), 0,
                     stream, z, W1, b1, h, NCOMP, HDIM, LDIM);
  // 3. raw = h @ W2 + b2          [32768,512]x[512,512]
  hipLaunchKernelGGL((gemm64<1, false>), dim3(HDIM / 64, NCOMP / 64), dim3(256), 0,
                     stream, h, W2, b2, raw, NCOMP, HDIM, HDIM);
  // 4. raw -> P (in place), cvec
  hipLaunchKernelGGL(params_kernel, dim3(NCOMP), dim3(256), 0, stream, raw, cvec);
  // 5. lp = X' @ P^T + c          [512,512]x[512,32768]
  hipLaunchKernelGGL((gemm64<1, true>), dim3(NCOMP / 64, BROWS / 64), dim3(256), 0,
                     stream, xp, raw, cvec, lp, BROWS, NCOMP, HDIM);
  // 6. top-16 per row, emit lp at selected indices
  hipLaunchKernelGGL(topk_kernel, dim3(BROWS), dim3(256), 0, stream, lp, log_w, out);
}

// Round 2
// 685.292 us; speedup vs baseline: 1.7708x; 1.7708x over previous
//
#include <hip/hip_runtime.h>
#include <math.h>

#define NCOMP 32768
#define LDIM  128
#define HDIM  512
#define DDIM  256
#define BROWS 512
#define KTOP  16

// -0.5 * D * log(2*pi)
#define NEG_HALF_D_LOG2PI (-235.24844f)

typedef short bf16x8 __attribute__((ext_vector_type(8)));
typedef float f32x4  __attribute__((ext_vector_type(4)));
typedef unsigned short ushort_t;
typedef unsigned int uint_t;

// ---------------- bf16 helpers (RNE) ----------------
__device__ __forceinline__ ushort_t f2bf(float f) {
  uint_t u = __float_as_uint(f);
  u = u + 0x7fffu + ((u >> 16) & 1u);
  return (ushort_t)(u >> 16);
}
__device__ __forceinline__ float bf2f(ushort_t h) {
  return __uint_as_float(((uint_t)h) << 16);
}

// ------------------------------------------------------------------
// Prep kernels
// ------------------------------------------------------------------
__global__ __launch_bounds__(256) void cast_z_kernel(const float* __restrict__ z,
                                                     ushort_t* __restrict__ z16) {
  int i = (blockIdx.x * 256 + threadIdx.x) * 4;   // over 32768*128
  float4 v = *(const float4*)&z[i];
  z16[i + 0] = f2bf(v.x);
  z16[i + 1] = f2bf(v.y);
  z16[i + 2] = f2bf(v.z);
  z16[i + 3] = f2bf(v.w);
}

// W [R][512] fp32 -> Wt [512][R] bf16  (C fixed at 512)
__global__ __launch_bounds__(256) void transpose_cast_kernel(const float* __restrict__ W,
                                                             ushort_t* __restrict__ Wt,
                                                             int R) {
  int i = blockIdx.x * 256 + threadIdx.x;  // R*512
  int r = i >> 9, c = i & 511;
  Wt[(size_t)c * R + r] = f2bf(W[i]);
}

// Xs [512][1536] bf16 : [hi(u) | hi(u) | lo(u)], u = [x^2 (256), x (256)]
__global__ __launch_bounds__(256) void xprime_split_kernel(const float* __restrict__ x,
                                                           ushort_t* __restrict__ Xs) {
  int i = blockIdx.x * 256 + threadIdx.x;   // 512*256
  int b = i >> 8, d = i & 255;
  float xv = x[i];
  float x2 = xv * xv;
  ushort_t h2 = f2bf(x2), h1 = f2bf(xv);
  float l2 = x2 - bf2f(h2), l1 = xv - bf2f(h1);
  size_t base = (size_t)b * 1536;
  Xs[base + d]        = h2;
  Xs[base + 256 + d]  = h1;
  Xs[base + 512 + d]  = h2;
  Xs[base + 768 + d]  = h1;
  Xs[base + 1024 + d] = f2bf(l2);
  Xs[base + 1280 + d] = f2bf(l1);
}

// raw [N][512] fp32 (mu | logvar) -> Ps [N][1024] bf16 : [hi(v) | lo(v)],
// v = [-0.5*inv_var (256), mu*inv_var (256)], plus cvec [N].
__global__ __launch_bounds__(256) void params_kernel(const float* __restrict__ raw,
                                                     ushort_t* __restrict__ Ps,
                                                     float* __restrict__ cvec) {
  const int n = blockIdx.x;
  const int d = threadIdx.x;
  size_t rb = (size_t)n * 512;
  float mu = raw[rb + d];
  float lv = raw[rb + 256 + d];
  float sp = (lv > 20.f) ? lv : log1pf(expf(lv));
  float sd = fminf(sp + 0.1f, 1.0f);      // sp>=0 so >=0.1 automatically
  float iv = 1.0f / (sd * sd);
  float v0 = -0.5f * iv;
  float v1 = mu * iv;
  size_t pb = (size_t)n * 1024;
  ushort_t h0 = f2bf(v0), h1 = f2bf(v1);
  Ps[pb + d]        = h0;
  Ps[pb + 256 + d]  = h1;
  Ps[pb + 512 + d]  = f2bf(v0 - bf2f(h0));
  Ps[pb + 768 + d]  = f2bf(v1 - bf2f(h1));

  float part = -0.5f * mu * mu * iv - logf(sd);
  #pragma unroll
  for (int off = 32; off > 0; off >>= 1) part += __shfl_down(part, off, 64);
  __shared__ float red[4];
  if ((d & 63) == 0) red[d >> 6] = part;
  __syncthreads();
  if (d == 0)
    cvec[n] = (red[0] + red[1] + red[2] + red[3]) + NEG_HALF_D_LOG2PI;
}

// ------------------------------------------------------------------
// bf16 MFMA GEMM: C[M,N] = epi(A[M,K] @ B[N,K]^T + bias[n])
// 128x128 tile, BK=32, 256 threads (4 waves, each 64x64 = 4x4 frags of
// 16x16x32). Reg-staged LDS with XOR swizzle (byte ^= (row&7)<<4).
// Segment table (kb0/kb1/kb2, sps = k-steps per segment) lets A run over
// a continuous K while B jumps (split-bf16 3-product trick).
// EPI: 0 = relu(+bias) -> bf16 out;  1 = +bias -> f32 out
// ------------------------------------------------------------------
template<int EPI>
__global__ __launch_bounds__(256) void gemm_mfma(
    const ushort_t* __restrict__ A, int lda,
    const ushort_t* __restrict__ B, int ldb,
    const float* __restrict__ bias,
    void* __restrict__ Cout, int ldc,
    int nsteps, int sps, int kb0, int kb1, int kb2) {
  __shared__ __align__(16) ushort_t As[4096];   // [128 rows][32 k] bf16 (swizzled)
  __shared__ __align__(16) ushort_t Bs[4096];

  const int tid = threadIdx.x;
  const int lane = tid & 63, wid = tid >> 6;
  const int wr = wid >> 1, wc = wid & 1;
  const int m0 = blockIdx.y * 128, n0 = blockIdx.x * 128;

  // staging: thread covers two 16B chunks at linear bytes tid*16 and 4096+tid*16
  const int s_row0 = tid >> 2;                 // rows 0..63
  const int s_col  = (tid & 3) * 8;            // ushort elements within 32-k row
  const int s_row1 = 64 + s_row0;
  const int w0 = (tid * 16) ^ ((s_row0 & 7) << 4);
  const int w1 = w0 ^ 4096;

  // fragment read addresses (constant across K loop)
  int aaddr[4], baddr[4];
  #pragma unroll
  for (int i = 0; i < 4; i++) {
    int ra = wr * 64 + i * 16 + (lane & 15);
    aaddr[i] = (ra * 64 + ((lane >> 4) * 16)) ^ ((ra & 7) << 4);
    int rb = wc * 64 + i * 16 + (lane & 15);
    baddr[i] = (rb * 64 + ((lane >> 4) * 16)) ^ ((rb & 7) << 4);
  }

  f32x4 acc[4][4];
  #pragma unroll
  for (int i = 0; i < 4; i++)
    #pragma unroll
    for (int j = 0; j < 4; j++)
      acc[i][j] = (f32x4){0.f, 0.f, 0.f, 0.f};

  int4 va0, va1, vb0, vb1;
  auto loadregs = [&](int step) {
    int kA = step << 5;
    int sg = step / sps;
    int kB = ((sg == 0) ? kb0 : ((sg == 1) ? kb1 : kb2)) + ((step - sg * sps) << 5);
    va0 = *(const int4*)(A + (size_t)(m0 + s_row0) * lda + kA + s_col);
    va1 = *(const int4*)(A + (size_t)(m0 + s_row1) * lda + kA + s_col);
    vb0 = *(const int4*)(B + (size_t)(n0 + s_row0) * ldb + kB + s_col);
    vb1 = *(const int4*)(B + (size_t)(n0 + s_row1) * ldb + kB + s_col);
  };

  loadregs(0);
  for (int step = 0; step < nsteps; ++step) {
    __syncthreads();                  // previous tile's reads complete
    *(int4*)((char*)As + w0) = va0;
    *(int4*)((char*)As + w1) = va1;
    *(int4*)((char*)Bs + w0) = vb0;
    *(int4*)((char*)Bs + w1) = vb1;
    __syncthreads();
    if (step + 1 < nsteps) loadregs(step + 1);   // issue next loads early (T14)

    bf16x8 af[4], bfr[4];
    #pragma unroll
    for (int i = 0; i < 4; i++)
      af[i] = *(const bf16x8*)((const char*)As + aaddr[i]);
    #pragma unroll
    for (int j = 0; j < 4; j++)
      bfr[j] = *(const bf16x8*)((const char*)Bs + baddr[j]);
    #pragma unroll
    for (int i = 0; i < 4; i++)
      #pragma unroll
      for (int j = 0; j < 4; j++)
        acc[i][j] = __builtin_amdgcn_mfma_f32_16x16x32_bf16(af[i], bfr[j], acc[i][j], 0, 0, 0);
  }

  // epilogue
  float bvals[4];
  #pragma unroll
  for (int j = 0; j < 4; j++)
    bvals[j] = bias[n0 + wc * 64 + j * 16 + (lane & 15)];
  #pragma unroll
  for (int i = 0; i < 4; i++) {
    int row = m0 + wr * 64 + i * 16 + ((lane >> 4) << 2);
    #pragma unroll
    for (int j = 0; j < 4; j++) {
      int col = n0 + wc * 64 + j * 16 + (lane & 15);
      #pragma unroll
      for (int r = 0; r < 4; r++) {
        float v = acc[i][j][r] + bvals[j];
        if (EPI == 0) {
          v = fmaxf(v, 0.f);
          ((ushort_t*)Cout)[(size_t)(row + r) * ldc + col] = f2bf(v);
        } else {
          ((float*)Cout)[(size_t)(row + r) * ldc + col] = v;
        }
      }
    }
  }
}

// ------------------------------------------------------------------
// Top-16 per row of scores = lp[b,:] + log_w[:]; output lp at chosen idx.
// Per-thread top-16 over 128 elems, then 8-round pairwise merge tree.
// Tie-break: lower index wins (matches jax.lax.top_k).
// ------------------------------------------------------------------
__device__ __forceinline__ bool beats(float s, int n, float v, int i) {
  return (s > v) || (s == v && n < i);
}

__device__ __forceinline__ void insert16(float (&v)[16], int (&id)[16],
                                         float s, int n) {
  if (!beats(s, n, v[15], id[15])) return;
  #pragma unroll
  for (int i = 15; i >= 1; --i) {
    bool up   = beats(s, n, v[i - 1], id[i - 1]);
    bool here = beats(s, n, v[i], id[i]);
    float nv = up ? v[i - 1] : (here ? s : v[i]);
    int   ni = up ? id[i - 1] : (here ? n : id[i]);
    v[i] = nv; id[i] = ni;
  }
  if (beats(s, n, v[0], id[0])) { v[0] = s; id[0] = n; }
}

__global__ __launch_bounds__(256) void topk_kernel(const float* __restrict__ lp,
                                                   const float* __restrict__ log_w,
                                                   float* __restrict__ out) {
  const int b = blockIdx.x;
  const int tid = threadIdx.x;
  const float* row = lp + (size_t)b * NCOMP;

  float v[16]; int id[16];
  #pragma unroll
  for (int i = 0; i < 16; i++) { v[i] = -INFINITY; id[i] = 0x7fffffff; }

  for (int c = 0; c < 32; ++c) {
    int n4 = (c * 256 + tid) * 4;
    float4 s4 = *(const float4*)&row[n4];
    float4 w4 = *(const float4*)&log_w[n4];
    insert16(v, id, s4.x + w4.x, n4 + 0);
    insert16(v, id, s4.y + w4.y, n4 + 1);
    insert16(v, id, s4.z + w4.z, n4 + 2);
    insert16(v, id, s4.w + w4.w, n4 + 3);
  }

  __shared__ float sv[256 * 16];
  __shared__ int   sid[256 * 16];
  #pragma unroll
  for (int i = 0; i < 16; i++) { sv[tid * 16 + i] = v[i]; sid[tid * 16 + i] = id[i]; }

  // pairwise merge tree: 256 sorted lists -> 1
  for (int width = 1; width < 256; width <<= 1) {
    __syncthreads();
    int pairs = 256 / (2 * width);
    if (tid < pairs) {
      int l0 = tid * 2 * width;
      int l1 = l0 + width;
      float mv[16]; int mi[16];
      int p = 0, q = 0;
      #pragma unroll
      for (int i = 0; i < 16; i++) {
        float av = (p < 16) ? sv[l0 * 16 + p] : -INFINITY;
        int   ai = (p < 16) ? sid[l0 * 16 + p] : 0x7fffffff;
        float bv = (q < 16) ? sv[l1 * 16 + q] : -INFINITY;
        int   bi = (q < 16) ? sid[l1 * 16 + q] : 0x7fffffff;
        bool ta = beats(av, ai, bv, bi);
        mv[i] = ta ? av : bv;
        mi[i] = ta ? ai : bi;
        p += ta ? 1 : 0;
        q += ta ? 0 : 1;
      }
      #pragma unroll
      for (int i = 0; i < 16; i++) { sv[l0 * 16 + i] = mv[i]; sid[l0 * 16 + i] = mi[i]; }
    }
  }
  __syncthreads();
  if (tid == 0) {
    #pragma unroll
    for (int i = 0; i < 16; i++)
      out[(size_t)b * KTOP + i] = row[sid[i]];
  }
}

// ------------------------------------------------------------------
extern "C" void kernel_launch(void* const* d_in, const int* in_sizes, int n_in,
                              void* d_out, int out_size, void* d_ws, size_t ws_size,
                              hipStream_t stream) {
  const float* x     = (const float*)d_in[0];
  const float* log_w = (const float*)d_in[1];
  const float* z     = (const float*)d_in[2];
  const float* W1    = (const float*)d_in[3];
  const float* b1    = (const float*)d_in[4];
  const float* W2    = (const float*)d_in[5];
  const float* b2    = (const float*)d_in[6];
  float* out = (float*)d_out;

  char* p = (char*)d_ws;
  float* raw   = (float*)p;    p += (size_t)NCOMP * 512 * 4;   // 64MB (reused as lp)
  float* cvec  = (float*)p;    p += (size_t)NCOMP * 4;
  ushort_t* Ps = (ushort_t*)p; p += (size_t)NCOMP * 1024 * 2;  // 64MB
  ushort_t* h16= (ushort_t*)p; p += (size_t)NCOMP * 512 * 2;   // 32MB
  ushort_t* z16= (ushort_t*)p; p += (size_t)NCOMP * 128 * 2;   // 8MB
  ushort_t* W1t= (ushort_t*)p; p += (size_t)512 * 128 * 2;
  ushort_t* W2t= (ushort_t*)p; p += (size_t)512 * 512 * 2;
  ushort_t* Xs = (ushort_t*)p; p += (size_t)512 * 1536 * 2;
  float* lp = raw;

  // prep
  hipLaunchKernelGGL(cast_z_kernel, dim3(NCOMP * LDIM / 1024), dim3(256), 0, stream, z, z16);
  hipLaunchKernelGGL(transpose_cast_kernel, dim3(LDIM * HDIM / 256), dim3(256), 0, stream, W1, W1t, LDIM);
  hipLaunchKernelGGL(transpose_cast_kernel, dim3(HDIM * HDIM / 256), dim3(256), 0, stream, W2, W2t, HDIM);
  hipLaunchKernelGGL(xprime_split_kernel, dim3(BROWS * DDIM / 256), dim3(256), 0, stream, x, Xs);

  // G1: h16 = relu(z16 @ W1t^T + b1)   [32768,128] x [512,128]^T
  hipLaunchKernelGGL((gemm_mfma<0>), dim3(HDIM / 128, NCOMP / 128), dim3(256), 0, stream,
                     z16, LDIM, W1t, LDIM, b1, h16, HDIM,
                     LDIM / 32, LDIM / 32, 0, 0, 0);
  // G2: raw = h16 @ W2t^T + b2         [32768,512] x [512,512]^T
  hipLaunchKernelGGL((gemm_mfma<1>), dim3(HDIM / 128, NCOMP / 128), dim3(256), 0, stream,
                     h16, HDIM, W2t, HDIM, b2, raw, HDIM,
                     HDIM / 32, HDIM / 32, 0, 0, 0);
  // params: raw -> Ps (split hi/lo), cvec
  hipLaunchKernelGGL(params_kernel, dim3(NCOMP), dim3(256), 0, stream, raw, Ps, cvec);
  // G3: lp = Xs @ Ps^T + cvec   (split-bf16 3-product, K=1536 over segments)
  //   seg0: A[0:512)  * B hi(kb=0); seg1: A[512:1024) * B lo(kb=512); seg2: A[1024:1536) * B hi(kb=0)
  hipLaunchKernelGGL((gemm_mfma<1>), dim3(NCOMP / 128, BROWS / 128), dim3(256), 0, stream,
                     Xs, 1536, Ps, 1024, cvec, lp, NCOMP,
                     48, 16, 0, 512, 0);
  // topk
  hipLaunchKernelGGL(topk_kernel, dim3(BROWS), dim3(256), 0, stream, lp, log_w, out);
}

// Round 3
// 462.294 us; speedup vs baseline: 2.6249x; 1.4824x over previous
//
#include <hip/hip_runtime.h>
#include <math.h>

#define NCOMP 32768
#define LDIM  128
#define HDIM  512
#define DDIM  256
#define BROWS 512
#define KTOP  16

// -0.5 * D * log(2*pi)
#define NEG_HALF_D_LOG2PI (-235.24844f)

typedef short bf16x8 __attribute__((ext_vector_type(8)));
typedef float f32x4  __attribute__((ext_vector_type(4)));
typedef unsigned short ushort_t;
typedef unsigned int uint_t;

// ---------------- bf16 helpers (RNE) ----------------
__device__ __forceinline__ ushort_t f2bf(float f) {
  uint_t u = __float_as_uint(f);
  u = u + 0x7fffu + ((u >> 16) & 1u);
  return (ushort_t)(u >> 16);
}
__device__ __forceinline__ float bf2f(ushort_t h) {
  return __uint_as_float(((uint_t)h) << 16);
}

// async global->LDS, 16B per lane. LDS dest is wave-uniform base + lane*16.
__device__ __forceinline__ void load_lds16(const ushort_t* g, ushort_t* l) {
  __builtin_amdgcn_global_load_lds(
      (const __attribute__((address_space(1))) unsigned int*)g,
      (__attribute__((address_space(3))) unsigned int*)l, 16, 0, 0);
}

// LDS swizzle in 16B-chunk space: f(c) = c ^ ((c>>2)&7)  (reads use f)
// inverse (for global_load_lds source pre-swizzle): g = f^-1(d)
__device__ __forceinline__ int inv_swz(int d) {
  return d ^ ((d >> 2) & 7) ^ ((d >> 4) & 1);
}

// ------------------------------------------------------------------
// Prep kernels
// ------------------------------------------------------------------
__global__ __launch_bounds__(256) void cast_z_kernel(const float* __restrict__ z,
                                                     ushort_t* __restrict__ z16) {
  int i = (blockIdx.x * 256 + threadIdx.x) * 4;   // over 32768*128
  float4 v = *(const float4*)&z[i];
  z16[i + 0] = f2bf(v.x);
  z16[i + 1] = f2bf(v.y);
  z16[i + 2] = f2bf(v.z);
  z16[i + 3] = f2bf(v.w);
}

// W [R][512] fp32 -> Wt [512][R] bf16
__global__ __launch_bounds__(256) void transpose_cast_kernel(const float* __restrict__ W,
                                                             ushort_t* __restrict__ Wt,
                                                             int R) {
  int i = blockIdx.x * 256 + threadIdx.x;  // R*512
  int r = i >> 9, c = i & 511;
  Wt[(size_t)c * R + r] = f2bf(W[i]);
}

// Xs [512][1536] bf16 : [hi(u) | hi(u) | lo(u)], u = [x^2 (256), x (256)]
__global__ __launch_bounds__(256) void xprime_split_kernel(const float* __restrict__ x,
                                                           ushort_t* __restrict__ Xs) {
  int i = blockIdx.x * 256 + threadIdx.x;   // 512*256
  int b = i >> 8, d = i & 255;
  float xv = x[i];
  float x2 = xv * xv;
  ushort_t h2 = f2bf(x2), h1 = f2bf(xv);
  float l2 = x2 - bf2f(h2), l1 = xv - bf2f(h1);
  size_t base = (size_t)b * 1536;
  Xs[base + d]        = h2;
  Xs[base + 256 + d]  = h1;
  Xs[base + 512 + d]  = h2;
  Xs[base + 768 + d]  = h1;
  Xs[base + 1024 + d] = f2bf(l2);
  Xs[base + 1280 + d] = f2bf(l1);
}

// raw [N][512] fp32 (mu | logvar) -> Ps [N][1024] bf16 : [hi(v) | lo(v)],
// v = [-0.5*inv_var (256), mu*inv_var (256)], plus cvec [N].
__global__ __launch_bounds__(256) void params_kernel(const float* __restrict__ raw,
                                                     ushort_t* __restrict__ Ps,
                                                     float* __restrict__ cvec) {
  const int n = blockIdx.x;
  const int d = threadIdx.x;
  size_t rb = (size_t)n * 512;
  float mu = raw[rb + d];
  float lv = raw[rb + 256 + d];
  float sp = (lv > 20.f) ? lv : log1pf(expf(lv));
  float sd = fminf(sp + 0.1f, 1.0f);
  float iv = 1.0f / (sd * sd);
  float v0 = -0.5f * iv;
  float v1 = mu * iv;
  size_t pb = (size_t)n * 1024;
  ushort_t h0 = f2bf(v0), h1 = f2bf(v1);
  Ps[pb + d]        = h0;
  Ps[pb + 256 + d]  = h1;
  Ps[pb + 512 + d]  = f2bf(v0 - bf2f(h0));
  Ps[pb + 768 + d]  = f2bf(v1 - bf2f(h1));

  float part = -0.5f * mu * mu * iv - logf(sd);
  #pragma unroll
  for (int off = 32; off > 0; off >>= 1) part += __shfl_down(part, off, 64);
  __shared__ float red[4];
  if ((d & 63) == 0) red[d >> 6] = part;
  __syncthreads();
  if (d == 0)
    cvec[n] = (red[0] + red[1] + red[2] + red[3]) + NEG_HALF_D_LOG2PI;
}

// ------------------------------------------------------------------
// bf16 MFMA GEMM: C[M,N] = epi(A[M,K] @ B[N,K]^T + bias[n])
// 128x128 tile, BK=32, 256 threads (4 waves 2x2, each 64x64 of 16x16x32).
// global_load_lds (16B) into double-buffered LDS; XOR swizzle applied by
// pre-swizzling the per-lane global source chunk (linear LDS dest).
// One barrier per K-step (T3 minimum 2-phase).
// Segment table (kb0/kb1/kb2, sps) lets B jump K-segments (split-bf16).
// MX=true: m-blocks on blockIdx.x (A-sharing siblings same XCD).
// EPI: 0 = relu(+bias) -> bf16 out;  1 = +bias -> f32 out
// ------------------------------------------------------------------
template<int EPI, bool MX>
__global__ __launch_bounds__(256) void gemm_mfma(
    const ushort_t* __restrict__ A, int lda,
    const ushort_t* __restrict__ B, int ldb,
    const float* __restrict__ bias,
    void* __restrict__ Cout, int ldc,
    int nsteps, int sps, int kb0, int kb1, int kb2) {
  __shared__ __align__(16) ushort_t As[2][4096];   // 8KB per buffer
  __shared__ __align__(16) ushort_t Bs[2][4096];

  const int tid = threadIdx.x;
  const int lane = tid & 63, wid = tid >> 6;
  const int wr = wid >> 1, wc = wid & 1;
  const int m0 = (MX ? blockIdx.x : blockIdx.y) * 128;
  const int n0 = (MX ? blockIdx.y : blockIdx.x) * 128;

  // ---- staging: thread owns dest chunks d0=tid, d1=256+tid (16B each) ----
  const int d0 = tid, d1 = 256 + tid;
  const int g0 = inv_swz(d0), g1 = inv_swz(d1);
  const ushort_t* pa0 = A + (size_t)(m0 + (g0 >> 2)) * lda + (g0 & 3) * 8;
  const ushort_t* pa1 = A + (size_t)(m0 + (g1 >> 2)) * lda + (g1 & 3) * 8;
  const ushort_t* pb0 = B + (size_t)(n0 + (g0 >> 2)) * ldb + (g0 & 3) * 8;
  const ushort_t* pb1 = B + (size_t)(n0 + (g1 >> 2)) * ldb + (g1 & 3) * 8;

  // ---- fragment read byte-offsets (swizzled), constant across K ----
  int aaddr[4], baddr[4];
  #pragma unroll
  for (int i = 0; i < 4; i++) {
    int ra = wr * 64 + i * 16 + (lane & 15);
    aaddr[i] = (ra * 64 + ((lane >> 4) * 16)) ^ ((ra & 7) << 4);
    int rb = wc * 64 + i * 16 + (lane & 15);
    baddr[i] = (rb * 64 + ((lane >> 4) * 16)) ^ ((rb & 7) << 4);
  }

  f32x4 acc[4][4];
  #pragma unroll
  for (int i = 0; i < 4; i++)
    #pragma unroll
    for (int j = 0; j < 4; j++)
      acc[i][j] = (f32x4){0.f, 0.f, 0.f, 0.f};

  auto stage = [&](int buf, int step) {
    int kA = step << 5;
    int sg = (step >= sps) ? ((step >= 2 * sps) ? 2 : 1) : 0;
    int kB = ((sg == 0) ? kb0 : ((sg == 1) ? kb1 : kb2)) + ((step - sg * sps) << 5);
    load_lds16(pa0 + kA, &As[buf][d0 * 8]);
    load_lds16(pa1 + kA, &As[buf][d1 * 8]);
    load_lds16(pb0 + kB, &Bs[buf][d0 * 8]);
    load_lds16(pb1 + kB, &Bs[buf][d1 * 8]);
  };

  stage(0, 0);
  __syncthreads();              // drains vmcnt -> buf0 ready

  int cur = 0;
  for (int step = 0; step < nsteps; ++step) {
    const bool pf = (step + 1 < nsteps);
    if (pf) stage(cur ^ 1, step + 1);   // loads fly during compute

    const char* Ab = (const char*)As + cur * 8192;
    const char* Bb = (const char*)Bs + cur * 8192;
    bf16x8 af[4], bfr[4];
    #pragma unroll
    for (int i = 0; i < 4; i++) af[i] = *(const bf16x8*)(Ab + aaddr[i]);
    #pragma unroll
    for (int j = 0; j < 4; j++) bfr[j] = *(const bf16x8*)(Bb + baddr[j]);
    #pragma unroll
    for (int i = 0; i < 4; i++)
      #pragma unroll
      for (int j = 0; j < 4; j++)
        acc[i][j] = __builtin_amdgcn_mfma_f32_16x16x32_bf16(af[i], bfr[j], acc[i][j], 0, 0, 0);

    if (pf) {
      __syncthreads();          // drains vmcnt (next buf ready) + lgkm
      cur ^= 1;
    }
  }

  // ---- epilogue (stores to same 128B line adjacent: j innermost) ----
  float bvals[4];
  #pragma unroll
  for (int j = 0; j < 4; j++)
    bvals[j] = bias[n0 + wc * 64 + j * 16 + (lane & 15)];
  #pragma unroll
  for (int i = 0; i < 4; i++) {
    int rowb = m0 + wr * 64 + i * 16 + ((lane >> 4) << 2);
    #pragma unroll
    for (int r = 0; r < 4; r++) {
      #pragma unroll
      for (int j = 0; j < 4; j++) {
        int col = n0 + wc * 64 + j * 16 + (lane & 15);
        float v = acc[i][j][r] + bvals[j];
        if (EPI == 0) {
          v = fmaxf(v, 0.f);
          ((ushort_t*)Cout)[(size_t)(rowb + r) * ldc + col] = f2bf(v);
        } else {
          ((float*)Cout)[(size_t)(rowb + r) * ldc + col] = v;
        }
      }
    }
  }
}

// ------------------------------------------------------------------
// Top-16 per row of scores = lp[b,:] + log_w[:]; output lp at chosen idx.
// Tie-break: lower index wins (matches jax.lax.top_k).
// ------------------------------------------------------------------
__device__ __forceinline__ bool beats(float s, int n, float v, int i) {
  return (s > v) || (s == v && n < i);
}

__device__ __forceinline__ void insert16(float (&v)[16], int (&id)[16],
                                         float s, int n) {
  if (!beats(s, n, v[15], id[15])) return;
  #pragma unroll
  for (int i = 15; i >= 1; --i) {
    bool up   = beats(s, n, v[i - 1], id[i - 1]);
    bool here = beats(s, n, v[i], id[i]);
    float nv = up ? v[i - 1] : (here ? s : v[i]);
    int   ni = up ? id[i - 1] : (here ? n : id[i]);
    v[i] = nv; id[i] = ni;
  }
  if (beats(s, n, v[0], id[0])) { v[0] = s; id[0] = n; }
}

__global__ __launch_bounds__(256) void topk_kernel(const float* __restrict__ lp,
                                                   const float* __restrict__ log_w,
                                                   float* __restrict__ out) {
  const int b = blockIdx.x;
  const int tid = threadIdx.x;
  const float* row = lp + (size_t)b * NCOMP;

  float v[16]; int id[16];
  #pragma unroll
  for (int i = 0; i < 16; i++) { v[i] = -INFINITY; id[i] = 0x7fffffff; }

  for (int c = 0; c < 32; ++c) {
    int n4 = (c * 256 + tid) * 4;
    float4 s4 = *(const float4*)&row[n4];
    float4 w4 = *(const float4*)&log_w[n4];
    insert16(v, id, s4.x + w4.x, n4 + 0);
    insert16(v, id, s4.y + w4.y, n4 + 1);
    insert16(v, id, s4.z + w4.z, n4 + 2);
    insert16(v, id, s4.w + w4.w, n4 + 3);
  }

  __shared__ float sv[256 * 16];
  __shared__ int   sid[256 * 16];
  #pragma unroll
  for (int i = 0; i < 16; i++) { sv[tid * 16 + i] = v[i]; sid[tid * 16 + i] = id[i]; }

  for (int width = 1; width < 256; width <<= 1) {
    __syncthreads();
    int pairs = 256 / (2 * width);
    if (tid < pairs) {
      int l0 = tid * 2 * width;
      int l1 = l0 + width;
      float mv[16]; int mi[16];
      int p = 0, q = 0;
      #pragma unroll
      for (int i = 0; i < 16; i++) {
        float av = (p < 16) ? sv[l0 * 16 + p] : -INFINITY;
        int   ai = (p < 16) ? sid[l0 * 16 + p] : 0x7fffffff;
        float bv = (q < 16) ? sv[l1 * 16 + q] : -INFINITY;
        int   bi = (q < 16) ? sid[l1 * 16 + q] : 0x7fffffff;
        bool ta = beats(av, ai, bv, bi);
        mv[i] = ta ? av : bv;
        mi[i] = ta ? ai : bi;
        p += ta ? 1 : 0;
        q += ta ? 0 : 1;
      }
      #pragma unroll
      for (int i = 0; i < 16; i++) { sv[l0 * 16 + i] = mv[i]; sid[l0 * 16 + i] = mi[i]; }
    }
  }
  __syncthreads();
  if (tid == 0) {
    #pragma unroll
    for (int i = 0; i < 16; i++)
      out[(size_t)b * KTOP + i] = row[sid[i]];
  }
}

// ------------------------------------------------------------------
extern "C" void kernel_launch(void* const* d_in, const int* in_sizes, int n_in,
                              void* d_out, int out_size, void* d_ws, size_t ws_size,
                              hipStream_t stream) {
  const float* x     = (const float*)d_in[0];
  const float* log_w = (const float*)d_in[1];
  const float* z     = (const float*)d_in[2];
  const float* W1    = (const float*)d_in[3];
  const float* b1    = (const float*)d_in[4];
  const float* W2    = (const float*)d_in[5];
  const float* b2    = (const float*)d_in[6];
  float* out = (float*)d_out;

  char* p = (char*)d_ws;
  float* raw   = (float*)p;    p += (size_t)NCOMP * 512 * 4;   // 64MB (reused as lp)
  float* cvec  = (float*)p;    p += (size_t)NCOMP * 4;
  ushort_t* Ps = (ushort_t*)p; p += (size_t)NCOMP * 1024 * 2;  // 64MB
  ushort_t* h16= (ushort_t*)p; p += (size_t)NCOMP * 512 * 2;   // 32MB
  ushort_t* z16= (ushort_t*)p; p += (size_t)NCOMP * 128 * 2;   // 8MB
  ushort_t* W1t= (ushort_t*)p; p += (size_t)512 * 128 * 2;
  ushort_t* W2t= (ushort_t*)p; p += (size_t)512 * 512 * 2;
  ushort_t* Xs = (ushort_t*)p; p += (size_t)512 * 1536 * 2;
  float* lp = raw;

  // prep
  hipLaunchKernelGGL(cast_z_kernel, dim3(NCOMP * LDIM / 1024), dim3(256), 0, stream, z, z16);
  hipLaunchKernelGGL(transpose_cast_kernel, dim3(LDIM * HDIM / 256), dim3(256), 0, stream, W1, W1t, LDIM);
  hipLaunchKernelGGL(transpose_cast_kernel, dim3(HDIM * HDIM / 256), dim3(256), 0, stream, W2, W2t, HDIM);
  hipLaunchKernelGGL(xprime_split_kernel, dim3(BROWS * DDIM / 256), dim3(256), 0, stream, x, Xs);

  // G1: h16 = relu(z16 @ W1t^T + b1)   [32768,128] x [512,128]^T  (m-blocks on x)
  hipLaunchKernelGGL((gemm_mfma<0, true>), dim3(NCOMP / 128, HDIM / 128), dim3(256), 0, stream,
                     z16, LDIM, W1t, LDIM, b1, h16, HDIM,
                     LDIM / 32, LDIM / 32, 0, 0, 0);
  // G2: raw = h16 @ W2t^T + b2         [32768,512] x [512,512]^T  (m-blocks on x)
  hipLaunchKernelGGL((gemm_mfma<1, true>), dim3(NCOMP / 128, HDIM / 128), dim3(256), 0, stream,
                     h16, HDIM, W2t, HDIM, b2, raw, HDIM,
                     HDIM / 32, HDIM / 32, 0, 0, 0);
  // params: raw -> Ps (split hi/lo), cvec
  hipLaunchKernelGGL(params_kernel, dim3(NCOMP), dim3(256), 0, stream, raw, Ps, cvec);
  // G3: lp = Xs @ Ps^T + cvec  (split-bf16 3-product, K=1536 over segments)
  hipLaunchKernelGGL((gemm_mfma<1, false>), dim3(NCOMP / 128, BROWS / 128), dim3(256), 0, stream,
                     Xs, 1536, Ps, 1024, cvec, lp, NCOMP,
                     48, 16, 0, 512, 0);
  // topk
  hipLaunchKernelGGL(topk_kernel, dim3(BROWS), dim3(256), 0, stream, lp, log_w, out);
}

// Round 5
// 349.583 us; speedup vs baseline: 3.4713x; 1.3224x over previous
//
#include <hip/hip_runtime.h>
#include <math.h>

#define NCOMP 32768
#define LDIM  128
#define HDIM  512
#define DDIM  256
#define BROWS 512
#define KTOP  16

// -0.5 * D * log(2*pi)
#define NEG_HALF_D_LOG2PI (-235.24844f)

typedef short bf16x8 __attribute__((ext_vector_type(8)));
typedef float f32x4  __attribute__((ext_vector_type(4)));
typedef unsigned short ushort_t;
typedef unsigned int uint_t;

// ---------------- bf16 helpers (RNE) ----------------
__device__ __forceinline__ ushort_t f2bf(float f) {
  uint_t u = __float_as_uint(f);
  u = u + 0x7fffu + ((u >> 16) & 1u);
  return (ushort_t)(u >> 16);
}
__device__ __forceinline__ float bf2f(ushort_t h) {
  return __uint_as_float(((uint_t)h) << 16);
}

// async global->LDS, 16B per lane. LDS dest is wave-uniform base + lane*16.
__device__ __forceinline__ void load_lds16(const ushort_t* g, ushort_t* l) {
  __builtin_amdgcn_global_load_lds(
      (const __attribute__((address_space(1))) unsigned int*)g,
      (__attribute__((address_space(3))) unsigned int*)l, 16, 0, 0);
}

// ------------------------------------------------------------------
// Prep kernels
// ------------------------------------------------------------------
__global__ __launch_bounds__(256) void cast_z_kernel(const float* __restrict__ z,
                                                     ushort_t* __restrict__ z16) {
  int i = (blockIdx.x * 256 + threadIdx.x) * 4;   // over 32768*128
  float4 v = *(const float4*)&z[i];
  z16[i + 0] = f2bf(v.x);
  z16[i + 1] = f2bf(v.y);
  z16[i + 2] = f2bf(v.z);
  z16[i + 3] = f2bf(v.w);
}

// W [R][512] fp32 -> Wt [512][R] bf16
__global__ __launch_bounds__(256) void transpose_cast_kernel(const float* __restrict__ W,
                                                             ushort_t* __restrict__ Wt,
                                                             int R) {
  int i = blockIdx.x * 256 + threadIdx.x;  // R*512
  int r = i >> 9, c = i & 511;
  Wt[(size_t)c * R + r] = f2bf(W[i]);
}

// Xs [512][1536] bf16 : [hi(u) | lo(u) | hi(u)], u = [x^2 (256), x (256)]
// (segment order hi,lo,hi so B reads its hi-slab twice back-to-back)
__global__ __launch_bounds__(256) void xprime_split_kernel(const float* __restrict__ x,
                                                           ushort_t* __restrict__ Xs) {
  int i = blockIdx.x * 256 + threadIdx.x;   // 512*256
  int b = i >> 8, d = i & 255;
  float xv = x[i];
  float x2 = xv * xv;
  ushort_t h2 = f2bf(x2), h1 = f2bf(xv);
  float l2 = x2 - bf2f(h2), l1 = xv - bf2f(h1);
  size_t base = (size_t)b * 1536;
  Xs[base + d]        = h2;
  Xs[base + 256 + d]  = h1;
  Xs[base + 512 + d]  = f2bf(l2);
  Xs[base + 768 + d]  = f2bf(l1);
  Xs[base + 1024 + d] = h2;
  Xs[base + 1280 + d] = h1;
}

// raw [N][512] fp32 (mu | logvar) -> Ps [N][1024] bf16 : [hi(v) | lo(v)],
// v = [-0.5*inv_var (256), mu*inv_var (256)], plus cvec [N].
// One wave per component; float4 loads, ushort4 stores.
__global__ __launch_bounds__(256) void params_kernel(const float* __restrict__ raw,
                                                     ushort_t* __restrict__ Ps,
                                                     float* __restrict__ cvec) {
  const int w = threadIdx.x >> 6, lane = threadIdx.x & 63;
  const int n = blockIdx.x * 4 + w;
  size_t rb = (size_t)n * 512;
  float4 mu4 = *(const float4*)(raw + rb + lane * 4);
  float4 lv4 = *(const float4*)(raw + rb + 256 + lane * 4);
  float mus[4] = {mu4.x, mu4.y, mu4.z, mu4.w};
  float lvs[4] = {lv4.x, lv4.y, lv4.z, lv4.w};
  ushort4 o0, o1, o2, o3;
  ushort_t* p0 = &o0.x; ushort_t* p1 = &o1.x;
  ushort_t* p2 = &o2.x; ushort_t* p3 = &o3.x;
  float part = 0.f;
  #pragma unroll
  for (int e = 0; e < 4; e++) {
    float lv = lvs[e];
    float sp = (lv > 20.f) ? lv : log1pf(expf(lv));
    float sd = fminf(sp + 0.1f, 1.0f);
    float iv = 1.0f / (sd * sd);
    float v0 = -0.5f * iv;
    float v1 = mus[e] * iv;
    ushort_t h0 = f2bf(v0), h1 = f2bf(v1);
    p0[e] = h0; p1[e] = h1;
    p2[e] = f2bf(v0 - bf2f(h0));
    p3[e] = f2bf(v1 - bf2f(h1));
    part += -0.5f * mus[e] * mus[e] * iv - logf(sd);
  }
  size_t pb = (size_t)n * 1024;
  *(ushort4*)(Ps + pb + lane * 4)       = o0;
  *(ushort4*)(Ps + pb + 256 + lane * 4) = o1;
  *(ushort4*)(Ps + pb + 512 + lane * 4) = o2;
  *(ushort4*)(Ps + pb + 768 + lane * 4) = o3;
  #pragma unroll
  for (int off = 32; off > 0; off >>= 1) part += __shfl_down(part, off, 64);
  if (lane == 0) cvec[n] = part + NEG_HALF_D_LOG2PI;
}

// ------------------------------------------------------------------
// 256x256 bf16 MFMA GEMM: C[M,N] = epi(A[M,K] @ B[N,K]^T + bias[n])
// BK=64, 512 threads (8 waves 2x4, each 128x64 = 8x4 frags of 16x16x32).
// Double-buffered 128KB LDS, global_load_lds 16B, full-row XOR swizzle:
// logical chunk (row,c) lives at physical chunk (row, c^(row&7)); applied
// via pre-swizzled global source (linear LDS dest).  Fragment reads
// compose the k-half offset with XOR (NOT add: the add carried bit6->bit7
// = row bit, which was round 4's inf bug).
// T3-minimum 2-phase: stage next -> compute cur -> one __syncthreads.
// Per-segment K-base tables for BOTH A and B (split-bf16 3-product).
// Flat grid with XCD-chunked bijective swizzle; nShort/shortIsM put
// panel-sharing sibling blocks adjacent (same XCD).
// EPI: 0 = relu(+bias) -> bf16 out;  1 = +bias -> f32 out
// ------------------------------------------------------------------
template<int EPI>
__global__ __launch_bounds__(512, 2) void gemm256(
    const ushort_t* __restrict__ A, int lda,
    const ushort_t* __restrict__ B, int ldb,
    const float* __restrict__ bias,
    void* __restrict__ Cout, int ldc,
    int nsteps, int sps,
    int kbA0, int kbA1, int kbA2,
    int kbB0, int kbB1, int kbB2,
    int nShort, int shortIsM) {
  __shared__ __align__(16) ushort_t As[2][16384];   // 32KB per buffer
  __shared__ __align__(16) ushort_t Bs[2][16384];

  const int tid = threadIdx.x;
  const int lane = tid & 63, wid = tid >> 6;
  const int wr = wid >> 2, wc = wid & 3;            // 2 x 4 wave grid

  // XCD-chunked bijective block swizzle (gridDim.x % 8 == 0)
  const int cpx = gridDim.x >> 3;
  const int newid = (blockIdx.x & 7) * cpx + (blockIdx.x >> 3);
  const int s = newid % nShort, l = newid / nShort;
  const int m0 = (shortIsM ? s : l) * 256;
  const int n0 = (shortIsM ? l : s) * 256;

  // ---- staging: 4 rounds per matrix; dest chunk p = r*512+tid (16B) ----
  // physical chunk p holds logical chunk (p&~7)|((p&7)^((p>>3)&7))
  const ushort_t* pA[4];
  const ushort_t* pB[4];
  #pragma unroll
  for (int r = 0; r < 4; r++) {
    int p = r * 512 + tid;
    int row = p >> 3;
    int col = ((p & 7) ^ (row & 7)) * 8;
    pA[r] = A + (size_t)(m0 + row) * lda + col;
    pB[r] = B + (size_t)(n0 + row) * ldb + col;
  }

  // ---- fragment read byte-offsets (swizzled); k-half composed via XOR ----
  int aoff[8], boff[4];
  #pragma unroll
  for (int i = 0; i < 8; i++) {
    int ra = wr * 128 + i * 16 + (lane & 15);
    aoff[i] = (ra * 128 + ((lane >> 4) * 16)) ^ ((ra & 7) << 4);
  }
  #pragma unroll
  for (int j = 0; j < 4; j++) {
    int rb = wc * 64 + j * 16 + (lane & 15);
    boff[j] = (rb * 128 + ((lane >> 4) * 16)) ^ ((rb & 7) << 4);
  }

  f32x4 acc[8][4];
  #pragma unroll
  for (int i = 0; i < 8; i++)
    #pragma unroll
    for (int j = 0; j < 4; j++)
      acc[i][j] = (f32x4){0.f, 0.f, 0.f, 0.f};

  auto stage = [&](int buf, int step) {
    int sg = (step >= sps) ? ((step >= 2 * sps) ? 2 : 1) : 0;
    int ks = (step - sg * sps) << 6;
    int kA = ((sg == 0) ? kbA0 : (sg == 1) ? kbA1 : kbA2) + ks;
    int kB = ((sg == 0) ? kbB0 : (sg == 1) ? kbB1 : kbB2) + ks;
    #pragma unroll
    for (int r = 0; r < 4; r++) {
      load_lds16(pA[r] + kA, &As[buf][(r * 512 + tid) * 8]);
      load_lds16(pB[r] + kB, &Bs[buf][(r * 512 + tid) * 8]);
    }
  };

  stage(0, 0);
  __syncthreads();              // vmcnt drain -> buf0 ready

  int cur = 0;
  for (int step = 0; step < nsteps; ++step) {
    if (step + 1 < nsteps) stage(cur ^ 1, step + 1);   // loads fly over compute

    const char* Ab = (const char*)As[cur];
    const char* Bb = (const char*)Bs[cur];
    #pragma unroll
    for (int kh = 0; kh < 2; ++kh) {
      bf16x8 af[8], bfr[4];
      #pragma unroll
      for (int i = 0; i < 8; i++) af[i] = *(const bf16x8*)(Ab + (aoff[i] ^ (kh << 6)));
      #pragma unroll
      for (int j = 0; j < 4; j++) bfr[j] = *(const bf16x8*)(Bb + (boff[j] ^ (kh << 6)));
      #pragma unroll
      for (int i = 0; i < 8; i++)
        #pragma unroll
        for (int j = 0; j < 4; j++)
          acc[i][j] = __builtin_amdgcn_mfma_f32_16x16x32_bf16(af[i], bfr[j], acc[i][j], 0, 0, 0);
    }
    __syncthreads();            // drains vmcnt (next buf ready) + lgkm
    cur ^= 1;
  }

  // ---- epilogue ----
  float bv[4];
  #pragma unroll
  for (int j = 0; j < 4; j++)
    bv[j] = bias[n0 + wc * 64 + j * 16 + (lane & 15)];
  #pragma unroll
  for (int i = 0; i < 8; i++) {
    int rowb = m0 + wr * 128 + i * 16 + ((lane >> 4) << 2);
    #pragma unroll
    for (int r = 0; r < 4; r++) {
      #pragma unroll
      for (int j = 0; j < 4; j++) {
        int col = n0 + wc * 64 + j * 16 + (lane & 15);
        float v = acc[i][j][r] + bv[j];
        if (EPI == 0) {
          v = fmaxf(v, 0.f);
          ((ushort_t*)Cout)[(size_t)(rowb + r) * ldc + col] = f2bf(v);
        } else {
          ((float*)Cout)[(size_t)(rowb + r) * ldc + col] = v;
        }
      }
    }
  }
}

// ------------------------------------------------------------------
// Top-16 per row of scores = lp[b,:] + log_w[:]; output lp at chosen idx.
// Tie-break: lower index wins (matches jax.lax.top_k).
// ------------------------------------------------------------------
__device__ __forceinline__ bool beats(float s, int n, float v, int i) {
  return (s > v) || (s == v && n < i);
}

__device__ __forceinline__ void insert16(float (&v)[16], int (&id)[16],
                                         float s, int n) {
  if (!beats(s, n, v[15], id[15])) return;
  #pragma unroll
  for (int i = 15; i >= 1; --i) {
    bool up   = beats(s, n, v[i - 1], id[i - 1]);
    bool here = beats(s, n, v[i], id[i]);
    float nv = up ? v[i - 1] : (here ? s : v[i]);
    int   ni = up ? id[i - 1] : (here ? n : id[i]);
    v[i] = nv; id[i] = ni;
  }
  if (beats(s, n, v[0], id[0])) { v[0] = s; id[0] = n; }
}

__global__ __launch_bounds__(256) void topk_kernel(const float* __restrict__ lp,
                                                   const float* __restrict__ log_w,
                                                   float* __restrict__ out) {
  const int b = blockIdx.x;
  const int tid = threadIdx.x;
  const float* row = lp + (size_t)b * NCOMP;

  float v[16]; int id[16];
  #pragma unroll
  for (int i = 0; i < 16; i++) { v[i] = -INFINITY; id[i] = 0x7fffffff; }

  for (int c = 0; c < 32; ++c) {
    int n4 = (c * 256 + tid) * 4;
    float4 s4 = *(const float4*)&row[n4];
    float4 w4 = *(const float4*)&log_w[n4];
    insert16(v, id, s4.x + w4.x, n4 + 0);
    insert16(v, id, s4.y + w4.y, n4 + 1);
    insert16(v, id, s4.z + w4.z, n4 + 2);
    insert16(v, id, s4.w + w4.w, n4 + 3);
  }

  __shared__ float sv[256 * 16];
  __shared__ int   sid[256 * 16];
  #pragma unroll
  for (int i = 0; i < 16; i++) { sv[tid * 16 + i] = v[i]; sid[tid * 16 + i] = id[i]; }

  for (int width = 1; width < 256; width <<= 1) {
    __syncthreads();
    int pairs = 256 / (2 * width);
    if (tid < pairs) {
      int l0 = tid * 2 * width;
      int l1 = l0 + width;
      float mv[16]; int mi[16];
      int p = 0, q = 0;
      #pragma unroll
      for (int i = 0; i < 16; i++) {
        float av = (p < 16) ? sv[l0 * 16 + p] : -INFINITY;
        int   ai = (p < 16) ? sid[l0 * 16 + p] : 0x7fffffff;
        float bv = (q < 16) ? sv[l1 * 16 + q] : -INFINITY;
        int   bi = (q < 16) ? sid[l1 * 16 + q] : 0x7fffffff;
        bool ta = beats(av, ai, bv, bi);
        mv[i] = ta ? av : bv;
        mi[i] = ta ? ai : bi;
        p += ta ? 1 : 0;
        q += ta ? 0 : 1;
      }
      #pragma unroll
      for (int i = 0; i < 16; i++) { sv[l0 * 16 + i] = mv[i]; sid[l0 * 16 + i] = mi[i]; }
    }
  }
  __syncthreads();
  if (tid == 0) {
    #pragma unroll
    for (int i = 0; i < 16; i++)
      out[(size_t)b * KTOP + i] = row[sid[i]];
  }
}

// ------------------------------------------------------------------
extern "C" void kernel_launch(void* const* d_in, const int* in_sizes, int n_in,
                              void* d_out, int out_size, void* d_ws, size_t ws_size,
                              hipStream_t stream) {
  const float* x     = (const float*)d_in[0];
  const float* log_w = (const float*)d_in[1];
  const float* z     = (const float*)d_in[2];
  const float* W1    = (const float*)d_in[3];
  const float* b1    = (const float*)d_in[4];
  const float* W2    = (const float*)d_in[5];
  const float* b2    = (const float*)d_in[6];
  float* out = (float*)d_out;

  char* p = (char*)d_ws;
  float* raw   = (float*)p;    p += (size_t)NCOMP * 512 * 4;   // 64MB (reused as lp)
  float* cvec  = (float*)p;    p += (size_t)NCOMP * 4;
  ushort_t* Ps = (ushort_t*)p; p += (size_t)NCOMP * 1024 * 2;  // 64MB
  ushort_t* h16= (ushort_t*)p; p += (size_t)NCOMP * 512 * 2;   // 32MB
  ushort_t* z16= (ushort_t*)p; p += (size_t)NCOMP * 128 * 2;   // 8MB
  ushort_t* W1t= (ushort_t*)p; p += (size_t)512 * 128 * 2;
  ushort_t* W2t= (ushort_t*)p; p += (size_t)512 * 512 * 2;
  ushort_t* Xs = (ushort_t*)p; p += (size_t)512 * 1536 * 2;
  float* lp = raw;

  // prep
  hipLaunchKernelGGL(cast_z_kernel, dim3(NCOMP * LDIM / 1024), dim3(256), 0, stream, z, z16);
  hipLaunchKernelGGL(transpose_cast_kernel, dim3(LDIM * HDIM / 256), dim3(256), 0, stream, W1, W1t, LDIM);
  hipLaunchKernelGGL(transpose_cast_kernel, dim3(HDIM * HDIM / 256), dim3(256), 0, stream, W2, W2t, HDIM);
  hipLaunchKernelGGL(xprime_split_kernel, dim3(BROWS * DDIM / 256), dim3(256), 0, stream, x, Xs);

  // G1: h16 = relu(z16 @ W1t^T + b1)   [32768,128] x [512,128]^T
  //     grid 128m x 2n = 256; siblings share A-panel (n fastest)
  hipLaunchKernelGGL((gemm256<0>), dim3(256), dim3(512), 0, stream,
                     z16, LDIM, W1t, LDIM, b1, h16, HDIM,
                     2, 2, 0, 0, 0, 0, 0, 0, 2, 0);
  // G2: raw = h16 @ W2t^T + b2         [32768,512] x [512,512]^T
  hipLaunchKernelGGL((gemm256<1>), dim3(256), dim3(512), 0, stream,
                     h16, HDIM, W2t, HDIM, b2, raw, HDIM,
                     8, 8, 0, 0, 0, 0, 0, 0, 2, 0);
  // params: raw -> Ps (split hi/lo), cvec
  hipLaunchKernelGGL(params_kernel, dim3(NCOMP / 4), dim3(256), 0, stream, raw, Ps, cvec);
  // G3: lp = Xs @ Ps^T + cvec  (split-bf16: hi*hi + lo*hi + hi*lo)
  //     A segs {0,512,1024} (hi,lo,hi); B segs {0,0,512} (hi,hi,lo)
  //     grid 2m x 128n = 256; siblings share B-panel (m fastest)
  hipLaunchKernelGGL((gemm256<1>), dim3(256), dim3(512), 0, stream,
                     Xs, 1536, Ps, 1024, cvec, lp, NCOMP,
                     24, 8, 0, 512, 1024, 0, 0, 512, 2, 1);
  // topk
  hipLaunchKernelGGL(topk_kernel, dim3(BROWS), dim3(256), 0, stream, lp, log_w, out);
}

// Round 6
// 234.648 us; speedup vs baseline: 5.1715x; 1.4898x over previous
//
#include <hip/hip_runtime.h>
#include <math.h>

#define NCOMP 32768
#define LDIM  128
#define HDIM  512
#define DDIM  256
#define BROWS 512
#define KTOP  16

// -0.5 * D * log(2*pi)
#define NEG_HALF_D_LOG2PI (-235.24844f)

typedef short bf16x8 __attribute__((ext_vector_type(8)));
typedef float f32x4  __attribute__((ext_vector_type(4)));
typedef unsigned short ushort_t;
typedef unsigned int uint_t;
typedef unsigned long long u64_t;

// ---------------- bf16 helpers (RNE) ----------------
__device__ __forceinline__ ushort_t f2bf(float f) {
  uint_t u = __float_as_uint(f);
  u = u + 0x7fffu + ((u >> 16) & 1u);
  return (ushort_t)(u >> 16);
}
__device__ __forceinline__ float bf2f(ushort_t h) {
  return __uint_as_float(((uint_t)h) << 16);
}

// async global->LDS, 16B per lane. LDS dest is wave-uniform base + lane*16.
__device__ __forceinline__ void load_lds16(const ushort_t* g, ushort_t* l) {
  __builtin_amdgcn_global_load_lds(
      (const __attribute__((address_space(1))) unsigned int*)g,
      (__attribute__((address_space(3))) unsigned int*)l, 16, 0, 0);
}

// ------------------------------------------------------------------
// Prep kernels
// ------------------------------------------------------------------
__global__ __launch_bounds__(256) void cast_z_kernel(const float* __restrict__ z,
                                                     ushort_t* __restrict__ z16) {
  int i = (blockIdx.x * 256 + threadIdx.x) * 4;   // over 32768*128
  float4 v = *(const float4*)&z[i];
  z16[i + 0] = f2bf(v.x);
  z16[i + 1] = f2bf(v.y);
  z16[i + 2] = f2bf(v.z);
  z16[i + 3] = f2bf(v.w);
}

// W [R][512] fp32 -> Wt [512][R] bf16
__global__ __launch_bounds__(256) void transpose_cast_kernel(const float* __restrict__ W,
                                                             ushort_t* __restrict__ Wt,
                                                             int R) {
  int i = blockIdx.x * 256 + threadIdx.x;  // R*512
  int r = i >> 9, c = i & 511;
  Wt[(size_t)c * R + r] = f2bf(W[i]);
}

// Xs [512][1536] bf16 : [hi(u) | lo(u) | hi(u)], u = [x^2 (256), x (256)]
__global__ __launch_bounds__(256) void xprime_split_kernel(const float* __restrict__ x,
                                                           ushort_t* __restrict__ Xs) {
  int i = blockIdx.x * 256 + threadIdx.x;   // 512*256
  int b = i >> 8, d = i & 255;
  float xv = x[i];
  float x2 = xv * xv;
  ushort_t h2 = f2bf(x2), h1 = f2bf(xv);
  float l2 = x2 - bf2f(h2), l1 = xv - bf2f(h1);
  size_t base = (size_t)b * 1536;
  Xs[base + d]        = h2;
  Xs[base + 256 + d]  = h1;
  Xs[base + 512 + d]  = f2bf(l2);
  Xs[base + 768 + d]  = f2bf(l1);
  Xs[base + 1024 + d] = h2;
  Xs[base + 1280 + d] = h1;
}

// raw [N][512] fp32 (mu | logvar) -> Ps [N][1024] bf16 : [hi(v) | lo(v)],
// v = [-0.5*inv_var (256), mu*inv_var (256)], plus cvec [N].
__global__ __launch_bounds__(256) void params_kernel(const float* __restrict__ raw,
                                                     ushort_t* __restrict__ Ps,
                                                     float* __restrict__ cvec) {
  const int w = threadIdx.x >> 6, lane = threadIdx.x & 63;
  const int n = blockIdx.x * 4 + w;
  size_t rb = (size_t)n * 512;
  float4 mu4 = *(const float4*)(raw + rb + lane * 4);
  float4 lv4 = *(const float4*)(raw + rb + 256 + lane * 4);
  float mus[4] = {mu4.x, mu4.y, mu4.z, mu4.w};
  float lvs[4] = {lv4.x, lv4.y, lv4.z, lv4.w};
  ushort4 o0, o1, o2, o3;
  ushort_t* p0 = &o0.x; ushort_t* p1 = &o1.x;
  ushort_t* p2 = &o2.x; ushort_t* p3 = &o3.x;
  float part = 0.f;
  #pragma unroll
  for (int e = 0; e < 4; e++) {
    float lv = lvs[e];
    float sp = (lv > 20.f) ? lv : log1pf(expf(lv));
    float sd = fminf(sp + 0.1f, 1.0f);
    float iv = 1.0f / (sd * sd);
    float v0 = -0.5f * iv;
    float v1 = mus[e] * iv;
    ushort_t h0 = f2bf(v0), h1 = f2bf(v1);
    p0[e] = h0; p1[e] = h1;
    p2[e] = f2bf(v0 - bf2f(h0));
    p3[e] = f2bf(v1 - bf2f(h1));
    part += -0.5f * mus[e] * mus[e] * iv - logf(sd);
  }
  size_t pb = (size_t)n * 1024;
  *(ushort4*)(Ps + pb + lane * 4)       = o0;
  *(ushort4*)(Ps + pb + 256 + lane * 4) = o1;
  *(ushort4*)(Ps + pb + 512 + lane * 4) = o2;
  *(ushort4*)(Ps + pb + 768 + lane * 4) = o3;
  #pragma unroll
  for (int off = 32; off > 0; off >>= 1) part += __shfl_down(part, off, 64);
  if (lane == 0) cvec[n] = part + NEG_HALF_D_LOG2PI;
}

// ------------------------------------------------------------------
// 256x256 bf16 MFMA GEMM (unchanged from round 5 — verified correct)
// ------------------------------------------------------------------
template<int EPI>
__global__ __launch_bounds__(512, 2) void gemm256(
    const ushort_t* __restrict__ A, int lda,
    const ushort_t* __restrict__ B, int ldb,
    const float* __restrict__ bias,
    void* __restrict__ Cout, int ldc,
    int nsteps, int sps,
    int kbA0, int kbA1, int kbA2,
    int kbB0, int kbB1, int kbB2,
    int nShort, int shortIsM) {
  __shared__ __align__(16) ushort_t As[2][16384];   // 32KB per buffer
  __shared__ __align__(16) ushort_t Bs[2][16384];

  const int tid = threadIdx.x;
  const int lane = tid & 63, wid = tid >> 6;
  const int wr = wid >> 2, wc = wid & 3;            // 2 x 4 wave grid

  // XCD-chunked bijective block swizzle (gridDim.x % 8 == 0)
  const int cpx = gridDim.x >> 3;
  const int newid = (blockIdx.x & 7) * cpx + (blockIdx.x >> 3);
  const int s = newid % nShort, l = newid / nShort;
  const int m0 = (shortIsM ? s : l) * 256;
  const int n0 = (shortIsM ? l : s) * 256;

  // ---- staging: 4 rounds per matrix; dest chunk p = r*512+tid (16B) ----
  const ushort_t* pA[4];
  const ushort_t* pB[4];
  #pragma unroll
  for (int r = 0; r < 4; r++) {
    int p = r * 512 + tid;
    int row = p >> 3;
    int col = ((p & 7) ^ (row & 7)) * 8;
    pA[r] = A + (size_t)(m0 + row) * lda + col;
    pB[r] = B + (size_t)(n0 + row) * ldb + col;
  }

  // ---- fragment read byte-offsets (swizzled); k-half composed via XOR ----
  int aoff[8], boff[4];
  #pragma unroll
  for (int i = 0; i < 8; i++) {
    int ra = wr * 128 + i * 16 + (lane & 15);
    aoff[i] = (ra * 128 + ((lane >> 4) * 16)) ^ ((ra & 7) << 4);
  }
  #pragma unroll
  for (int j = 0; j < 4; j++) {
    int rb = wc * 64 + j * 16 + (lane & 15);
    boff[j] = (rb * 128 + ((lane >> 4) * 16)) ^ ((rb & 7) << 4);
  }

  f32x4 acc[8][4];
  #pragma unroll
  for (int i = 0; i < 8; i++)
    #pragma unroll
    for (int j = 0; j < 4; j++)
      acc[i][j] = (f32x4){0.f, 0.f, 0.f, 0.f};

  auto stage = [&](int buf, int step) {
    int sg = (step >= sps) ? ((step >= 2 * sps) ? 2 : 1) : 0;
    int ks = (step - sg * sps) << 6;
    int kA = ((sg == 0) ? kbA0 : (sg == 1) ? kbA1 : kbA2) + ks;
    int kB = ((sg == 0) ? kbB0 : (sg == 1) ? kbB1 : kbB2) + ks;
    #pragma unroll
    for (int r = 0; r < 4; r++) {
      load_lds16(pA[r] + kA, &As[buf][(r * 512 + tid) * 8]);
      load_lds16(pB[r] + kB, &Bs[buf][(r * 512 + tid) * 8]);
    }
  };

  stage(0, 0);
  __syncthreads();              // vmcnt drain -> buf0 ready

  int cur = 0;
  for (int step = 0; step < nsteps; ++step) {
    if (step + 1 < nsteps) stage(cur ^ 1, step + 1);   // loads fly over compute

    const char* Ab = (const char*)As[cur];
    const char* Bb = (const char*)Bs[cur];
    #pragma unroll
    for (int kh = 0; kh < 2; ++kh) {
      bf16x8 af[8], bfr[4];
      #pragma unroll
      for (int i = 0; i < 8; i++) af[i] = *(const bf16x8*)(Ab + (aoff[i] ^ (kh << 6)));
      #pragma unroll
      for (int j = 0; j < 4; j++) bfr[j] = *(const bf16x8*)(Bb + (boff[j] ^ (kh << 6)));
      #pragma unroll
      for (int i = 0; i < 8; i++)
        #pragma unroll
        for (int j = 0; j < 4; j++)
          acc[i][j] = __builtin_amdgcn_mfma_f32_16x16x32_bf16(af[i], bfr[j], acc[i][j], 0, 0, 0);
    }
    __syncthreads();            // drains vmcnt (next buf ready) + lgkm
    cur ^= 1;
  }

  // ---- epilogue ----
  float bv[4];
  #pragma unroll
  for (int j = 0; j < 4; j++)
    bv[j] = bias[n0 + wc * 64 + j * 16 + (lane & 15)];
  #pragma unroll
  for (int i = 0; i < 8; i++) {
    int rowb = m0 + wr * 128 + i * 16 + ((lane >> 4) << 2);
    #pragma unroll
    for (int r = 0; r < 4; r++) {
      #pragma unroll
      for (int j = 0; j < 4; j++) {
        int col = n0 + wc * 64 + j * 16 + (lane & 15);
        float v = acc[i][j][r] + bv[j];
        if (EPI == 0) {
          v = fmaxf(v, 0.f);
          ((ushort_t*)Cout)[(size_t)(rowb + r) * ldc + col] = f2bf(v);
        } else {
          ((float*)Cout)[(size_t)(rowb + r) * ldc + col] = v;
        }
      }
    }
  }
}

// ------------------------------------------------------------------
// Top-16: wave-cooperative ballot-filtered select.
// Key = (sortable_u32(score) << 32) | (0xFFFFFFFF - idx): bigger key =
// higher score, ties -> lower index (== jax.lax.top_k order).
// Each wave keeps a lane-distributed sorted top-16 (lane j = j-th largest)
// + threshold theta = 16th (shfl lane 15). Scan: key > theta? -> ballot ->
// serialize rare insertions (one shfl_up shift step each). Deterministic:
// insertion order is (iteration, lane) order; final result is an exact
// total order, independent of scheduling.
// ------------------------------------------------------------------
__device__ __forceinline__ u64_t shfl_up1_u64(u64_t v) {
  uint_t lo = (uint_t)v, hi = (uint_t)(v >> 32);
  lo = __shfl_up(lo, 1, 64); hi = __shfl_up(hi, 1, 64);
  return ((u64_t)hi << 32) | lo;
}
__device__ __forceinline__ u64_t shfl_u64(u64_t v, int src) {
  uint_t lo = (uint_t)v, hi = (uint_t)(v >> 32);
  lo = __shfl(lo, src, 64); hi = __shfl(hi, src, 64);
  return ((u64_t)hi << 32) | lo;
}
// insert cand into the lane-distributed descending sorted list
__device__ __forceinline__ void insert_step(u64_t& key, u64_t cand, int lane) {
  u64_t kup = shfl_up1_u64(key);
  if (lane == 0) kup = ~0ULL;
  if (cand > key) key = (cand > kup) ? kup : cand;
}

__global__ __launch_bounds__(256) void topk_kernel(const float* __restrict__ lp,
                                                   const float* __restrict__ log_w,
                                                   float* __restrict__ out) {
  const int b = blockIdx.x;
  const int tid = threadIdx.x;
  const int w = tid >> 6, lane = tid & 63;
  const float* row = lp + (size_t)b * NCOMP;

  u64_t key = 0;       // sentinel: smaller than any real key
  u64_t theta = 0;

  const int base = w * 8192;
  for (int c = 0; c < 32; ++c) {
    int n0 = base + c * 256 + lane * 4;
    float4 s4 = *(const float4*)&row[n0];
    float4 w4 = *(const float4*)&log_w[n0];
    float ss[4] = {s4.x + w4.x, s4.y + w4.y, s4.z + w4.z, s4.w + w4.w};
    #pragma unroll
    for (int e = 0; e < 4; e++) {
      uint_t u = __float_as_uint(ss[e]);
      u = (u & 0x80000000u) ? ~u : (u | 0x80000000u);
      u64_t k = ((u64_t)u << 32) | (u64_t)(0xFFFFFFFFu - (uint_t)(n0 + e));
      u64_t m = __ballot(k > theta);
      if (m) {
        do {
          int src = __ffsll((long long)m) - 1;
          m &= m - 1;
          u64_t cand = shfl_u64(k, src);
          insert_step(key, cand, lane);
        } while (m);
        theta = shfl_u64(key, 15);
      }
    }
  }

  // ---- block merge: 4 wave-lists of 16 -> wave 0 ----
  __shared__ u64_t sk[64];
  if (lane < 16) sk[w * 16 + lane] = key;
  __syncthreads();
  if (w == 0) {
    u64_t th = shfl_u64(key, 15);
    for (int t = 16; t < 64; ++t) {
      u64_t cand = sk[t];            // uniform LDS read (broadcast)
      if (cand > th) {
        insert_step(key, cand, lane);
        th = shfl_u64(key, 15);
      }
    }
    if (lane < 16) {
      uint_t idx = 0xFFFFFFFFu - (uint_t)key;
      out[(size_t)b * KTOP + lane] = row[idx];
    }
  }
}

// ------------------------------------------------------------------
extern "C" void kernel_launch(void* const* d_in, const int* in_sizes, int n_in,
                              void* d_out, int out_size, void* d_ws, size_t ws_size,
                              hipStream_t stream) {
  const float* x     = (const float*)d_in[0];
  const float* log_w = (const float*)d_in[1];
  const float* z     = (const float*)d_in[2];
  const float* W1    = (const float*)d_in[3];
  const float* b1    = (const float*)d_in[4];
  const float* W2    = (const float*)d_in[5];
  const float* b2    = (const float*)d_in[6];
  float* out = (float*)d_out;

  char* p = (char*)d_ws;
  float* raw   = (float*)p;    p += (size_t)NCOMP * 512 * 4;   // 64MB (reused as lp)
  float* cvec  = (float*)p;    p += (size_t)NCOMP * 4;
  ushort_t* Ps = (ushort_t*)p; p += (size_t)NCOMP * 1024 * 2;  // 64MB
  ushort_t* h16= (ushort_t*)p; p += (size_t)NCOMP * 512 * 2;   // 32MB
  ushort_t* z16= (ushort_t*)p; p += (size_t)NCOMP * 128 * 2;   // 8MB
  ushort_t* W1t= (ushort_t*)p; p += (size_t)512 * 128 * 2;
  ushort_t* W2t= (ushort_t*)p; p += (size_t)512 * 512 * 2;
  ushort_t* Xs = (ushort_t*)p; p += (size_t)512 * 1536 * 2;
  float* lp = raw;

  // prep
  hipLaunchKernelGGL(cast_z_kernel, dim3(NCOMP * LDIM / 1024), dim3(256), 0, stream, z, z16);
  hipLaunchKernelGGL(transpose_cast_kernel, dim3(LDIM * HDIM / 256), dim3(256), 0, stream, W1, W1t, LDIM);
  hipLaunchKernelGGL(transpose_cast_kernel, dim3(HDIM * HDIM / 256), dim3(256), 0, stream, W2, W2t, HDIM);
  hipLaunchKernelGGL(xprime_split_kernel, dim3(BROWS * DDIM / 256), dim3(256), 0, stream, x, Xs);

  // G1: h16 = relu(z16 @ W1t^T + b1)   [32768,128] x [512,128]^T
  hipLaunchKernelGGL((gemm256<0>), dim3(256), dim3(512), 0, stream,
                     z16, LDIM, W1t, LDIM, b1, h16, HDIM,
                     2, 2, 0, 0, 0, 0, 0, 0, 2, 0);
  // G2: raw = h16 @ W2t^T + b2         [32768,512] x [512,512]^T
  hipLaunchKernelGGL((gemm256<1>), dim3(256), dim3(512), 0, stream,
                     h16, HDIM, W2t, HDIM, b2, raw, HDIM,
                     8, 8, 0, 0, 0, 0, 0, 0, 2, 0);
  // params: raw -> Ps (split hi/lo), cvec
  hipLaunchKernelGGL(params_kernel, dim3(NCOMP / 4), dim3(256), 0, stream, raw, Ps, cvec);
  // G3: lp = Xs @ Ps^T + cvec  (split-bf16: hi*hi + lo*hi + hi*lo)
  hipLaunchKernelGGL((gemm256<1>), dim3(256), dim3(512), 0, stream,
                     Xs, 1536, Ps, 1024, cvec, lp, NCOMP,
                     24, 8, 0, 512, 1024, 0, 0, 512, 2, 1);
  // topk
  hipLaunchKernelGGL(topk_kernel, dim3(BROWS), dim3(256), 0, stream, lp, log_w, out);
}